// Round 2
// baseline (214.143 us; speedup 1.0000x reference)
//
#include <hip/hip_runtime.h>

// Problem shape (fixed by the reference): B=128, D=1024.
// d_in[0] = h_mean [B,D] f32, d_in[1] = h_cov [B,D,D] f32.
// d_out   = a_mean [B*D] f32 ++ a_cov [B*D*D] f32 (tuple concatenated flat).

#define DDIM 1024
#define D4   256   // float4 per row

typedef float f32x4 __attribute__((ext_vector_type(4)));

__device__ __forceinline__ float gelu_cdf(float x) {
    // Phi(x) = 0.5*(1+erf(x/sqrt(2))) — exact erf formulation (approximate=False)
    return 0.5f * (1.0f + erff(x * 0.70710678118654752440f));
}

__device__ __forceinline__ float gelu_grad(float x) {
    // g'(x) = Phi(x) + x * phi(x),  phi(x) = exp(-x^2/2)/sqrt(2*pi)
    return gelu_cdf(x) + x * 0.39894228040143267794f * expf(-0.5f * x * x);
}

// Kernel A: a_mean = x*Phi(x); nabla = g'(x). One element per thread. ~3 µs.
__global__ void mean_nabla_kernel(const float* __restrict__ h_mean,
                                  float* __restrict__ a_mean,
                                  float* __restrict__ nabla, int n) {
    int i = blockIdx.x * blockDim.x + threadIdx.x;
    if (i >= n) return;
    float x = h_mean[i];
    float cdf = gelu_cdf(x);
    a_mean[i] = x * cdf;
    nabla[i] = cdf + x * 0.39894228040143267794f * expf(-0.5f * x * x);
}

// Kernel B: grid-stride over rows; one block (256 thr × float4) covers one
// 1024-col row per iteration. h_cov/a_cov are streamed non-temporally (read-
// once/write-once — keep them out of the caches); nabla stays cached (512 KiB,
// reused 1024×).  a_cov[n,i,l] = nabla[n,i] * h_cov[n,i,l] * nabla[n,l]
__global__ void __launch_bounds__(256) sandwich_kernel(
        const f32x4* __restrict__ h_cov,
        const float* __restrict__ nabla,
        f32x4* __restrict__ a_cov, int nrows) {
    const f32x4* __restrict__ nab4 = (const f32x4*)nabla;
    for (int row = blockIdx.x; row < nrows; row += gridDim.x) {
        const float s = nabla[row];                         // wave-uniform
        const f32x4 nl = nab4[((row >> 10) << 8) + threadIdx.x];  // cached
        const size_t idx = (size_t)row * D4 + threadIdx.x;
        f32x4 c = __builtin_nontemporal_load(&h_cov[idx]);
        f32x4 r;
        r.x = s * c.x * nl.x;
        r.y = s * c.y * nl.y;
        r.z = s * c.z * nl.z;
        r.w = s * c.w * nl.w;
        __builtin_nontemporal_store(r, &a_cov[idx]);
    }
}

// Fallback (only if ws_size is too small): a_mean only.
__global__ void mean_only_kernel(const float* __restrict__ h_mean,
                                 float* __restrict__ a_mean, int n) {
    int i = blockIdx.x * blockDim.x + threadIdx.x;
    if (i >= n) return;
    float x = h_mean[i];
    a_mean[i] = x * gelu_cdf(x);
}

// Fallback sandwich: recompute g' inline.
__global__ void __launch_bounds__(256) sandwich_fused_kernel(
        const float* __restrict__ h_cov,
        const float* __restrict__ h_mean,
        float* __restrict__ a_cov) {
    const int row = blockIdx.x;
    const int n = row >> 10;
    const float s = gelu_grad(h_mean[row]);
    const size_t base = (size_t)row * DDIM;
    const float4 c  = ((const float4*)(h_cov + base))[threadIdx.x];
    const float4 hm = ((const float4*)(h_mean + (size_t)n * DDIM))[threadIdx.x];
    float4 r;
    r.x = s * c.x * gelu_grad(hm.x);
    r.y = s * c.y * gelu_grad(hm.y);
    r.z = s * c.z * gelu_grad(hm.z);
    r.w = s * c.w * gelu_grad(hm.w);
    ((float4*)(a_cov + base))[threadIdx.x] = r;
}

extern "C" void kernel_launch(void* const* d_in, const int* in_sizes, int n_in,
                              void* d_out, int out_size, void* d_ws, size_t ws_size,
                              hipStream_t stream) {
    const float* h_mean = (const float*)d_in[0];
    const float* h_cov  = (const float*)d_in[1];
    float* out = (float*)d_out;

    const int BD = in_sizes[0];       // B*D = 131072 rows
    float* a_mean = out;              // first BD floats
    float* a_cov  = out + BD;         // next BD*D floats

    if (ws_size >= (size_t)BD * sizeof(float)) {
        float* nabla = (float*)d_ws;
        mean_nabla_kernel<<<(BD + 255) / 256, 256, 0, stream>>>(h_mean, a_mean, nabla, BD);
        // 8192 blocks = 32 blocks/CU queued; 16 rows per block, grid-stride.
        sandwich_kernel<<<8192, 256, 0, stream>>>(
            (const f32x4*)h_cov, nabla, (f32x4*)a_cov, BD);
    } else {
        mean_only_kernel<<<(BD + 255) / 256, 256, 0, stream>>>(h_mean, a_mean, BD);
        sandwich_fused_kernel<<<BD, 256, 0, stream>>>(h_cov, h_mean, a_cov);
    }
}

// Round 3
// 199.737 us; speedup vs baseline: 1.0721x; 1.0721x over previous
//
#include <hip/hip_runtime.h>

// Problem shape (fixed by the reference): B=128, D=1024.
// d_in[0] = h_mean [B,D] f32, d_in[1] = h_cov [B,D,D] f32.
// d_out   = a_mean [B*D] f32 ++ a_cov [B*D*D] f32 (tuple concatenated flat).

#define DDIM 1024
#define D4   256   // float4 per row
#define RPB  4     // rows per block (all within one batch n: 1024 % 4 == 0)

typedef float f32x4 __attribute__((ext_vector_type(4)));

__device__ __forceinline__ float gelu_cdf(float x) {
    // Phi(x) = 0.5*(1+erf(x/sqrt(2))) — exact erf formulation (approximate=False)
    return 0.5f * (1.0f + erff(x * 0.70710678118654752440f));
}

__device__ __forceinline__ float gelu_grad(float x) {
    // g'(x) = Phi(x) + x * phi(x),  phi(x) = exp(-x^2/2)/sqrt(2*pi)
    return gelu_cdf(x) + x * 0.39894228040143267794f * expf(-0.5f * x * x);
}

// Kernel A: a_mean = x*Phi(x); nabla = g'(x). One element per thread. ~3 µs.
__global__ void mean_nabla_kernel(const float* __restrict__ h_mean,
                                  float* __restrict__ a_mean,
                                  float* __restrict__ nabla, int n) {
    int i = blockIdx.x * blockDim.x + threadIdx.x;
    if (i >= n) return;
    float x = h_mean[i];
    float cdf = gelu_cdf(x);
    a_mean[i] = x * cdf;
    nabla[i] = cdf + x * 0.39894228040143267794f * expf(-0.5f * x * x);
}

// Kernel B: one block per 4 consecutive rows (same n). 256 threads × float4
// per row. 5 loads + 4 stores in flight per thread (MLP), nl shared across
// the 4 rows, s0..s3 are consecutive -> scalar dwordx4 load.
// a_cov[n,i,l] = nabla[n,i] * h_cov[n,i,l] * nabla[n,l]
__global__ void __launch_bounds__(256) sandwich_kernel(
        const f32x4* __restrict__ h_cov,
        const float* __restrict__ nabla,
        f32x4* __restrict__ a_cov) {
    const int row0 = blockIdx.x * RPB;
    const int n = row0 >> 10;
    const f32x4 nl = ((const f32x4*)nabla)[(n << 8) + threadIdx.x];  // cached
    const size_t base = (size_t)row0 * D4 + threadIdx.x;
    f32x4 c0 = h_cov[base];
    f32x4 c1 = h_cov[base + D4];
    f32x4 c2 = h_cov[base + 2 * D4];
    f32x4 c3 = h_cov[base + 3 * D4];
    const float s0 = nabla[row0];        // wave-uniform -> s_load
    const float s1 = nabla[row0 + 1];
    const float s2 = nabla[row0 + 2];
    const float s3 = nabla[row0 + 3];
    f32x4 r0, r1, r2, r3;
    r0.x = s0 * c0.x * nl.x; r0.y = s0 * c0.y * nl.y;
    r0.z = s0 * c0.z * nl.z; r0.w = s0 * c0.w * nl.w;
    r1.x = s1 * c1.x * nl.x; r1.y = s1 * c1.y * nl.y;
    r1.z = s1 * c1.z * nl.z; r1.w = s1 * c1.w * nl.w;
    r2.x = s2 * c2.x * nl.x; r2.y = s2 * c2.y * nl.y;
    r2.z = s2 * c2.z * nl.z; r2.w = s2 * c2.w * nl.w;
    r3.x = s3 * c3.x * nl.x; r3.y = s3 * c3.y * nl.y;
    r3.z = s3 * c3.z * nl.z; r3.w = s3 * c3.w * nl.w;
    a_cov[base] = r0;
    a_cov[base + D4] = r1;
    a_cov[base + 2 * D4] = r2;
    a_cov[base + 3 * D4] = r3;
}

// Fallback (only if ws_size is too small): a_mean only.
__global__ void mean_only_kernel(const float* __restrict__ h_mean,
                                 float* __restrict__ a_mean, int n) {
    int i = blockIdx.x * blockDim.x + threadIdx.x;
    if (i >= n) return;
    float x = h_mean[i];
    a_mean[i] = x * gelu_cdf(x);
}

// Fallback sandwich: recompute g' inline.
__global__ void __launch_bounds__(256) sandwich_fused_kernel(
        const float* __restrict__ h_cov,
        const float* __restrict__ h_mean,
        float* __restrict__ a_cov) {
    const int row = blockIdx.x;
    const int n = row >> 10;
    const float s = gelu_grad(h_mean[row]);
    const size_t base = (size_t)row * DDIM;
    const float4 c  = ((const float4*)(h_cov + base))[threadIdx.x];
    const float4 hm = ((const float4*)(h_mean + (size_t)n * DDIM))[threadIdx.x];
    float4 r;
    r.x = s * c.x * gelu_grad(hm.x);
    r.y = s * c.y * gelu_grad(hm.y);
    r.z = s * c.z * gelu_grad(hm.z);
    r.w = s * c.w * gelu_grad(hm.w);
    ((float4*)(a_cov + base))[threadIdx.x] = r;
}

extern "C" void kernel_launch(void* const* d_in, const int* in_sizes, int n_in,
                              void* d_out, int out_size, void* d_ws, size_t ws_size,
                              hipStream_t stream) {
    const float* h_mean = (const float*)d_in[0];
    const float* h_cov  = (const float*)d_in[1];
    float* out = (float*)d_out;

    const int BD = in_sizes[0];       // B*D = 131072 rows
    float* a_mean = out;              // first BD floats
    float* a_cov  = out + BD;         // next BD*D floats

    if (ws_size >= (size_t)BD * sizeof(float)) {
        float* nabla = (float*)d_ws;
        mean_nabla_kernel<<<(BD + 255) / 256, 256, 0, stream>>>(h_mean, a_mean, nabla, BD);
        sandwich_kernel<<<BD / RPB, 256, 0, stream>>>(
            (const f32x4*)h_cov, nabla, (f32x4*)a_cov);
    } else {
        mean_only_kernel<<<(BD + 255) / 256, 256, 0, stream>>>(h_mean, a_mean, BD);
        sandwich_fused_kernel<<<BD, 256, 0, stream>>>(h_cov, h_mean, a_cov);
    }
}

// Round 4
// 184.094 us; speedup vs baseline: 1.1632x; 1.0850x over previous
//
#include <hip/hip_runtime.h>

// Problem shape (fixed by the reference): B=128, D=1024.
// d_in[0] = h_mean [B,D] f32, d_in[1] = h_cov [B,D,D] f32.
// d_out   = a_mean [B*D] f32 ++ a_cov [B*D*D] f32 (tuple concatenated flat).

#define DDIM 1024
#define D4   256   // float4 per row

typedef float f32x4 __attribute__((ext_vector_type(4)));

__device__ __forceinline__ float gelu_cdf(float x) {
    // Phi(x) = 0.5*(1+erf(x/sqrt(2))) — exact erf formulation (approximate=False)
    return 0.5f * (1.0f + erff(x * 0.70710678118654752440f));
}

__device__ __forceinline__ float gelu_grad(float x) {
    // g'(x) = Phi(x) + x * phi(x),  phi(x) = exp(-x^2/2)/sqrt(2*pi)
    return gelu_cdf(x) + x * 0.39894228040143267794f * expf(-0.5f * x * x);
}

// Kernel A: a_mean = x*Phi(x); nabla = g'(x). One element per thread. ~3 µs.
__global__ void mean_nabla_kernel(const float* __restrict__ h_mean,
                                  float* __restrict__ a_mean,
                                  float* __restrict__ nabla, int n) {
    int i = blockIdx.x * blockDim.x + threadIdx.x;
    if (i >= n) return;
    float x = h_mean[i];
    float cdf = gelu_cdf(x);
    a_mean[i] = x * cdf;
    nabla[i] = cdf + x * 0.39894228040143267794f * expf(-0.5f * x * x);
}

// Kernel B (R1 structure + NT load): one block per (n,i) row; 256 thr × float4.
// h_cov read is non-temporal (read-once, keep L2 for the write stream);
// nabla row read stays cached (512 KiB, reused 1024x); store default-cached.
// a_cov[n,i,l] = nabla[n,i] * h_cov[n,i,l] * nabla[n,l]
__global__ void __launch_bounds__(256) sandwich_kernel(
        const f32x4* __restrict__ h_cov,
        const float* __restrict__ nabla,
        f32x4* __restrict__ a_cov) {
    const int row = blockIdx.x;            // row = n*D + i, 0..B*D-1
    const int n = row >> 10;               // / DDIM
    const float s = nabla[row];            // wave-uniform
    const size_t idx = (size_t)row * D4 + threadIdx.x;
    const f32x4 c  = __builtin_nontemporal_load(&h_cov[idx]);
    const f32x4 nl = ((const f32x4*)nabla)[(n << 8) + threadIdx.x];
    f32x4 r;
    r.x = s * c.x * nl.x;
    r.y = s * c.y * nl.y;
    r.z = s * c.z * nl.z;
    r.w = s * c.w * nl.w;
    a_cov[idx] = r;
}

// Fallback (only if ws_size is too small): a_mean only.
__global__ void mean_only_kernel(const float* __restrict__ h_mean,
                                 float* __restrict__ a_mean, int n) {
    int i = blockIdx.x * blockDim.x + threadIdx.x;
    if (i >= n) return;
    float x = h_mean[i];
    a_mean[i] = x * gelu_cdf(x);
}

// Fallback sandwich: recompute g' inline.
__global__ void __launch_bounds__(256) sandwich_fused_kernel(
        const float* __restrict__ h_cov,
        const float* __restrict__ h_mean,
        float* __restrict__ a_cov) {
    const int row = blockIdx.x;
    const int n = row >> 10;
    const float s = gelu_grad(h_mean[row]);
    const size_t base = (size_t)row * DDIM;
    const float4 c  = ((const float4*)(h_cov + base))[threadIdx.x];
    const float4 hm = ((const float4*)(h_mean + (size_t)n * DDIM))[threadIdx.x];
    float4 r;
    r.x = s * c.x * gelu_grad(hm.x);
    r.y = s * c.y * gelu_grad(hm.y);
    r.z = s * c.z * gelu_grad(hm.z);
    r.w = s * c.w * gelu_grad(hm.w);
    ((float4*)(a_cov + base))[threadIdx.x] = r;
}

extern "C" void kernel_launch(void* const* d_in, const int* in_sizes, int n_in,
                              void* d_out, int out_size, void* d_ws, size_t ws_size,
                              hipStream_t stream) {
    const float* h_mean = (const float*)d_in[0];
    const float* h_cov  = (const float*)d_in[1];
    float* out = (float*)d_out;

    const int BD = in_sizes[0];       // B*D = 131072 rows
    float* a_mean = out;              // first BD floats
    float* a_cov  = out + BD;         // next BD*D floats

    if (ws_size >= (size_t)BD * sizeof(float)) {
        float* nabla = (float*)d_ws;
        mean_nabla_kernel<<<(BD + 255) / 256, 256, 0, stream>>>(h_mean, a_mean, nabla, BD);
        sandwich_kernel<<<BD, 256, 0, stream>>>(
            (const f32x4*)h_cov, nabla, (f32x4*)a_cov);
    } else {
        mean_only_kernel<<<(BD + 255) / 256, 256, 0, stream>>>(h_mean, a_mean, BD);
        sandwich_fused_kernel<<<BD, 256, 0, stream>>>(h_cov, h_mean, a_cov);
    }
}

// Round 5
// 178.979 us; speedup vs baseline: 1.1965x; 1.0286x over previous
//
#include <hip/hip_runtime.h>

// Problem shape (fixed by the reference): B=128, D=1024.
// d_in[0] = h_mean [B,D] f32, d_in[1] = h_cov [B,D,D] f32.
// d_out   = a_mean [B*D] f32 ++ a_cov [B*D*D] f32 (tuple concatenated flat).

#define DDIM 1024
#define D4   256   // float4 per row

typedef float f32x4 __attribute__((ext_vector_type(4)));

__device__ __forceinline__ float gelu_cdf(float x) {
    // Phi(x) = 0.5*(1+erf(x/sqrt(2))) — exact erf formulation (approximate=False)
    return 0.5f * (1.0f + erff(x * 0.70710678118654752440f));
}

__device__ __forceinline__ float gelu_grad(float x) {
    // g'(x) = Phi(x) + x * phi(x),  phi(x) = exp(-x^2/2)/sqrt(2*pi)
    return gelu_cdf(x) + x * 0.39894228040143267794f * expf(-0.5f * x * x);
}

// Kernel A: a_mean = x*Phi(x); nabla = g'(x). One element per thread. ~3 µs.
__global__ void mean_nabla_kernel(const float* __restrict__ h_mean,
                                  float* __restrict__ a_mean,
                                  float* __restrict__ nabla, int n) {
    int i = blockIdx.x * blockDim.x + threadIdx.x;
    if (i >= n) return;
    float x = h_mean[i];
    float cdf = gelu_cdf(x);
    a_mean[i] = x * cdf;
    nabla[i] = cdf + x * 0.39894228040143267794f * expf(-0.5f * x * x);
}

// Kernel B (R4 + NT store): one block per (n,i) row; 256 thr × float4.
// h_cov read AND a_cov write are non-temporal (read-once / write-once streams
// — keep all 1 GiB out of L2); only the hot 512 KiB nabla stays cached.
// a_cov[n,i,l] = nabla[n,i] * h_cov[n,i,l] * nabla[n,l]
__global__ void __launch_bounds__(256) sandwich_kernel(
        const f32x4* __restrict__ h_cov,
        const float* __restrict__ nabla,
        f32x4* __restrict__ a_cov) {
    const int row = blockIdx.x;            // row = n*D + i, 0..B*D-1
    const int n = row >> 10;               // / DDIM
    const float s = nabla[row];            // wave-uniform
    const size_t idx = (size_t)row * D4 + threadIdx.x;
    const f32x4 c  = __builtin_nontemporal_load(&h_cov[idx]);
    const f32x4 nl = ((const f32x4*)nabla)[(n << 8) + threadIdx.x];
    f32x4 r;
    r.x = s * c.x * nl.x;
    r.y = s * c.y * nl.y;
    r.z = s * c.z * nl.z;
    r.w = s * c.w * nl.w;
    __builtin_nontemporal_store(r, &a_cov[idx]);
}

// Fallback (only if ws_size is too small): a_mean only.
__global__ void mean_only_kernel(const float* __restrict__ h_mean,
                                 float* __restrict__ a_mean, int n) {
    int i = blockIdx.x * blockDim.x + threadIdx.x;
    if (i >= n) return;
    float x = h_mean[i];
    a_mean[i] = x * gelu_cdf(x);
}

// Fallback sandwich: recompute g' inline.
__global__ void __launch_bounds__(256) sandwich_fused_kernel(
        const float* __restrict__ h_cov,
        const float* __restrict__ h_mean,
        float* __restrict__ a_cov) {
    const int row = blockIdx.x;
    const int n = row >> 10;
    const float s = gelu_grad(h_mean[row]);
    const size_t base = (size_t)row * DDIM;
    const float4 c  = ((const float4*)(h_cov + base))[threadIdx.x];
    const float4 hm = ((const float4*)(h_mean + (size_t)n * DDIM))[threadIdx.x];
    float4 r;
    r.x = s * c.x * gelu_grad(hm.x);
    r.y = s * c.y * gelu_grad(hm.y);
    r.z = s * c.z * gelu_grad(hm.z);
    r.w = s * c.w * gelu_grad(hm.w);
    ((float4*)(a_cov + base))[threadIdx.x] = r;
}

extern "C" void kernel_launch(void* const* d_in, const int* in_sizes, int n_in,
                              void* d_out, int out_size, void* d_ws, size_t ws_size,
                              hipStream_t stream) {
    const float* h_mean = (const float*)d_in[0];
    const float* h_cov  = (const float*)d_in[1];
    float* out = (float*)d_out;

    const int BD = in_sizes[0];       // B*D = 131072 rows
    float* a_mean = out;              // first BD floats
    float* a_cov  = out + BD;         // next BD*D floats

    if (ws_size >= (size_t)BD * sizeof(float)) {
        float* nabla = (float*)d_ws;
        mean_nabla_kernel<<<(BD + 255) / 256, 256, 0, stream>>>(h_mean, a_mean, nabla, BD);
        sandwich_kernel<<<BD, 256, 0, stream>>>(
            (const f32x4*)h_cov, nabla, (f32x4*)a_cov);
    } else {
        mean_only_kernel<<<(BD + 255) / 256, 256, 0, stream>>>(h_mean, a_mean, BD);
        sandwich_fused_kernel<<<BD, 256, 0, stream>>>(h_cov, h_mean, a_cov);
    }
}